// Round 8
// baseline (359.309 us; speedup 1.0000x reference)
//
#include <hip/hip_runtime.h>
#include <hip/hip_bf16.h>
#include <stdint.h>

// Problem dims (fixed by reference): B=64, T=512, H=1024, A=300
#define B_DIM 64
#define T_DIM 512
#define H_DIM 1024
#define K_DIM 1024
#define M_DIM (B_DIM * T_DIM)  // 32768 rows of the big GEMM
#define IG 4

typedef __bf16 bf16x8 __attribute__((ext_vector_type(8)));
typedef float f32x4 __attribute__((ext_vector_type(4)));

__device__ __forceinline__ float tanh_fast(float x) {
  float e = __expf(2.0f * x);
  return 1.0f - 2.0f / (e + 1.0f);
}

__device__ __forceinline__ float bf2f(unsigned short u) {
  return __uint_as_float(((unsigned int)u) << 16);
}

// async global->LDS, 16B per lane. LDS dest must be wave-uniform base + lane*16.
__device__ __forceinline__ void async_cp16(const void* gp, void* lp) {
  __builtin_amdgcn_global_load_lds(
      reinterpret_cast<const __attribute__((address_space(1))) uint32_t*>(
          reinterpret_cast<uintptr_t>(gp)),
      reinterpret_cast<__attribute__((address_space(3))) uint32_t*>(
          reinterpret_cast<uintptr_t>(lp)),
      16, 0, 0);
}

__device__ __forceinline__ void cvt4(const float4& v, uint2* dst) {
  union { __bf16 b[4]; uint2 u; } o;
  o.b[0] = (__bf16)v.x; o.b[1] = (__bf16)v.y; o.b[2] = (__bf16)v.z; o.b[3] = (__bf16)v.w;
  *dst = o.u;
}

// fence-pinned raw barrier (no vmcnt drain, unlike __syncthreads)
__device__ __forceinline__ void phase_barrier() {
  __builtin_amdgcn_sched_barrier(0);
  __builtin_amdgcn_s_barrier();
  __builtin_amdgcn_sched_barrier(0);
}

// ---- prep: cvt hidden + cvt W_h. Grid-stride, 2048 blocks (G11). ----
#define STRIDE_NTHR (2048 * 256)
__global__ void prep_kernel(const float* __restrict__ hidden, __bf16* __restrict__ hidBf,
                            const float* __restrict__ Wh, __bf16* __restrict__ whBf) {
  const int gt = blockIdx.x * 256 + threadIdx.x;  // 524288 threads
  const float4* hs = reinterpret_cast<const float4*>(hidden);
  uint2* hd = reinterpret_cast<uint2*>(hidBf);
#pragma unroll 4
  for (int i = gt; i < 8388608; i += STRIDE_NTHR) {  // 16 iters exact
    cvt4(hs[i], &hd[i]);
  }
  const float4* wsrc = reinterpret_cast<const float4*>(Wh);
  uint2* wd = reinterpret_cast<uint2*>(whBf);
  if (gt < 262144) cvt4(wsrc[gt], &wd[gt]);  // W_h: 262144 float4
}

// =============== gemm8: 8-phase-style pipelined GEMM + tanh + dot -> scoresP ===============
// R7 skeleton (verified correct: geometry 256x256/8 waves/BK=32, 4 LDS buffers,
// prefetch distance 3, vmcnt(8) accounting, XOR swizzle, epilogue) + the m201
// per-phase schedule R7 lacked (m196: the fine interleave IS the lever):
//   phase A: read bf x4 + af0 x4 (8 ds_read_b128) | stageA(t+3) | bar |
//            setprio 16 MFMA | bar
//   phase B: read af1 x4 (4 ds_read_b128)         | stageB(t+3) | bar |
//            setprio 16 MFMA | vmcnt(8) bar
// Trailing vmcnt per tile: 8 (main, t<=28), 4 (t=29), 0 (t=30), none (t=31) —
// same landing/overwrite proof as R7 (stage@t targets buf[(t-1)&3], freed by
// t's entry barrier; tile t+1's loads forced by the vmcnt(8) at t's tail).
// sched_barrier(0) around every raw s_barrier pins compiler code motion.
__global__ __launch_bounds__(512, 1) void gemm8_kernel(
    const __bf16* __restrict__ A, const __bf16* __restrict__ Bm,
    const float* __restrict__ bh, const float* __restrict__ ww,
    float* __restrict__ scoresP) {
  __shared__ __attribute__((aligned(16))) __bf16 lA[4 * 8192];  // 64 KB
  __shared__ __attribute__((aligned(16))) __bf16 lB[4 * 8192];  // 64 KB
  const int tid = threadIdx.x;
  const int bid = blockIdx.x;
  const int m0 = (bid & 127) * 256;   // consecutive bids share n-panel (A L2 reuse)
  const int nIdx = bid >> 7;          // 0..3
  const int n0 = nIdx * 256;
  const int wid = tid >> 6, lane = tid & 63;
  const int wm = wid >> 2, wn = wid & 3;
  const int r16 = lane & 15, quad = lane >> 4;
  const int sw2 = (r16 >> 1) & 3;

  // staging: thread covers chunks c = j*512+tid; row=c>>2, phys p=c&3,
  // logical kc = p ^ ((row>>1)&3). LDS dest = buf + c*16B (lane-contiguous).
  int srow[2], skc[2];
#pragma unroll
  for (int j = 0; j < 2; ++j) {
    int c = j * 512 + tid;
    srow[j] = c >> 2;
    skc[j] = (c & 3) ^ ((srow[j] >> 1) & 3);
  }
  // fragment read offsets (elems). row = base+r16 => (row>>1)&3 == sw2.
  int offA[8], offB[4];
#pragma unroll
  for (int mi = 0; mi < 8; ++mi)
    offA[mi] = (wm * 128 + mi * 16 + r16) * 32 + (quad ^ sw2) * 8;
#pragma unroll
  for (int ni = 0; ni < 4; ++ni)
    offB[ni] = (wn * 64 + ni * 16 + r16) * 32 + (quad ^ sw2) * 8;

  auto stageA = [&](int ts, int bs) {
#pragma unroll
    for (int j = 0; j < 2; ++j)
      async_cp16(A + (size_t)(m0 + srow[j]) * K_DIM + ts * 32 + skc[j] * 8,
                 lA + bs * 8192 + (j * 512 + tid) * 8);
  };
  auto stageB = [&](int ts, int bs) {
#pragma unroll
    for (int j = 0; j < 2; ++j)
      async_cp16(Bm + (size_t)(n0 + srow[j]) * K_DIM + ts * 32 + skc[j] * 8,
                 lB + bs * 8192 + (j * 512 + tid) * 8);
  };

  f32x4 acc[8][4] = {};

  // vmTail: 8 = main loop, 4/0 = drain, -1 = none (last tile)
  auto tile = [&](int t, bool st, int vmTail) {
    const __bf16* lab = lA + (t & 3) * 8192;
    const __bf16* lbb = lB + (t & 3) * 8192;
    // ---- phase A: 8 ds_reads | stage A(t+3) | bar | 16 MFMA | bar ----
    bf16x8 bf[4];
#pragma unroll
    for (int ni = 0; ni < 4; ++ni)
      bf[ni] = *reinterpret_cast<const bf16x8*>(lbb + offB[ni]);
    bf16x8 af0[4];
#pragma unroll
    for (int mi = 0; mi < 4; ++mi)
      af0[mi] = *reinterpret_cast<const bf16x8*>(lab + offA[mi]);
    if (st) stageA(t + 3, (t + 3) & 3);
    phase_barrier();
    __builtin_amdgcn_s_setprio(1);
#pragma unroll
    for (int mi = 0; mi < 4; ++mi)
#pragma unroll
      for (int ni = 0; ni < 4; ++ni)
        acc[mi][ni] = __builtin_amdgcn_mfma_f32_16x16x32_bf16(af0[mi], bf[ni], acc[mi][ni], 0, 0, 0);
    __builtin_amdgcn_s_setprio(0);
    phase_barrier();
    // ---- phase B: 4 ds_reads | stage B(t+3) | bar | 16 MFMA | vmcnt, bar ----
    bf16x8 af1[4];
#pragma unroll
    for (int mi = 0; mi < 4; ++mi)
      af1[mi] = *reinterpret_cast<const bf16x8*>(lab + offA[4 + mi]);
    if (st) stageB(t + 3, (t + 3) & 3);
    phase_barrier();
    __builtin_amdgcn_s_setprio(1);
#pragma unroll
    for (int mi = 0; mi < 4; ++mi)
#pragma unroll
      for (int ni = 0; ni < 4; ++ni)
        acc[4 + mi][ni] = __builtin_amdgcn_mfma_f32_16x16x32_bf16(af1[mi], bf[ni], acc[4 + mi][ni], 0, 0, 0);
    __builtin_amdgcn_s_setprio(0);
    __builtin_amdgcn_sched_barrier(0);
    if (vmTail == 8) asm volatile("s_waitcnt vmcnt(8)" ::: "memory");
    else if (vmTail == 4) asm volatile("s_waitcnt vmcnt(4)" ::: "memory");
    else if (vmTail == 0) asm volatile("s_waitcnt vmcnt(0)" ::: "memory");
    __builtin_amdgcn_s_barrier();
    __builtin_amdgcn_sched_barrier(0);
  };

  // prologue: stage tiles 0,1,2 (12 loads/wave in flight); land tile 0
  stageA(0, 0); stageB(0, 0);
  stageA(1, 1); stageB(1, 1);
  stageA(2, 2); stageB(2, 2);
  __builtin_amdgcn_sched_barrier(0);
  asm volatile("s_waitcnt vmcnt(8)" ::: "memory");
  __builtin_amdgcn_s_barrier();
  __builtin_amdgcn_sched_barrier(0);

#pragma unroll 1
  for (int t = 0; t < 29; ++t) tile(t, true, 8);
  tile(29, false, 4);
  tile(30, false, 0);
  tile(31, false, -1);
  __syncthreads();

  // ---- fused epilogue: tanh + dot(ww) + 16-lane shfl + 4-way wn LDS reduction ----
  float* sBuf = reinterpret_cast<float*>(lA);  // 4 KB scratch, safe after syncthreads
  float bhv[4], wwv[4];
#pragma unroll
  for (int ni = 0; ni < 4; ++ni) {
    int n = n0 + wn * 64 + ni * 16 + r16;
    bhv[ni] = bh[n];
    wwv[ni] = ww[n];
  }
#pragma unroll
  for (int mi = 0; mi < 8; ++mi) {
#pragma unroll
    for (int rg = 0; rg < 4; ++rg) {
      float s = 0.f;
#pragma unroll
      for (int ni = 0; ni < 4; ++ni)
        s += tanh_fast(acc[mi][ni][rg] + bhv[ni]) * wwv[ni];
      s += __shfl_xor(s, 1, 16);
      s += __shfl_xor(s, 2, 16);
      s += __shfl_xor(s, 4, 16);
      s += __shfl_xor(s, 8, 16);
      if (r16 == 0) sBuf[wn * 256 + wm * 128 + mi * 16 + quad * 4 + rg] = s;
    }
  }
  __syncthreads();
  if (tid < 256) {
    scoresP[nIdx * M_DIM + m0 + tid] =
        sBuf[tid] + sBuf[256 + tid] + sBuf[512 + tid] + sBuf[768 + tid];
  }
}

// ------- wsum: softmax (sums 4 n-panel partials) + weighted-sum partials, 512 blocks -------
__global__ void wsum_kernel(const float* __restrict__ scoresP,
                            const __bf16* __restrict__ hiddenBf,
                            float* __restrict__ r8) {
  __shared__ float sc[512];
  __shared__ float al[64];
  __shared__ float red[8];
  const int bid = blockIdx.x, tid = threadIdx.x;
  const int b = bid >> 3, tc = bid & 7;
  const int wv = tid >> 6, lane = tid & 63;
  float v0 = 0.f, v1 = 0.f;
#pragma unroll
  for (int p = 0; p < 4; ++p) {
    v0 += scoresP[p * M_DIM + b * T_DIM + tid];
    v1 += scoresP[p * M_DIM + b * T_DIM + 256 + tid];
  }
  sc[tid] = v0;
  sc[tid + 256] = v1;
  float mx = fmaxf(v0, v1);
#pragma unroll
  for (int off = 1; off < 64; off <<= 1) mx = fmaxf(mx, __shfl_xor(mx, off, 64));
  if (lane == 0) red[wv] = mx;
  __syncthreads();
  mx = fmaxf(fmaxf(red[0], red[1]), fmaxf(red[2], red[3]));
  float e0 = __expf(v0 - mx), e1 = __expf(v1 - mx);
  float s = e0 + e1;
#pragma unroll
  for (int off = 1; off < 64; off <<= 1) s += __shfl_xor(s, off, 64);
  if (lane == 0) red[4 + wv] = s;
  __syncthreads();
  float inv = 1.0f / (red[4] + red[5] + red[6] + red[7]);
  if (tid < 64) al[tid] = __expf(sc[tc * 64 + tid] - mx) * inv;
  __syncthreads();
  const __bf16* hp = hiddenBf + (size_t)b * T_DIM * H_DIM + (size_t)tc * 64 * H_DIM + tid * 4;
  float4 acc = make_float4(0.f, 0.f, 0.f, 0.f);
#pragma unroll 8
  for (int t = 0; t < 64; ++t) {
    float a = al[t];
    ushort4 u = *reinterpret_cast<const ushort4*>(hp + (size_t)t * H_DIM);
    acc.x += a * bf2f(u.x);
    acc.y += a * bf2f(u.y);
    acc.z += a * bf2f(u.z);
    acc.w += a * bf2f(u.w);
  }
  *reinterpret_cast<float4*>(r8 + (size_t)(b * 8 + tc) * H_DIM + tid * 4) = acc;
}

// ---- rp = (sum_tc r8) @ W_p^T + b_p ; xq = hidden[:,-1,:] @ W_x^T + b_x ----
__global__ void rowvec2_kernel(const float* __restrict__ r8,
                               const float* __restrict__ hidden,
                               const float* __restrict__ W_p, const float* __restrict__ b_p,
                               const float* __restrict__ W_x, const float* __restrict__ b_x,
                               float* __restrict__ rp, float* __restrict__ xq) {
  __shared__ __attribute__((aligned(16))) float sv[IG][H_DIM];
  const int h0 = blockIdx.x * 64;
  const int i0 = blockIdx.y * IG;
  const int which = blockIdx.z;
  const int tid = threadIdx.x;
  const float* W = which ? W_x : W_p;
  const float* bias = which ? b_x : b_p;
  float* dst = which ? xq : rp;
  if (which == 0) {
#pragma unroll
    for (int ii = 0; ii < IG; ++ii) {
      const float* src = r8 + (size_t)(i0 + ii) * 8 * H_DIM + tid * 4;
      float4 a = *reinterpret_cast<const float4*>(src);
#pragma unroll
      for (int tc = 1; tc < 8; ++tc) {
        float4 v = *reinterpret_cast<const float4*>(src + (size_t)tc * H_DIM);
        a.x += v.x; a.y += v.y; a.z += v.z; a.w += v.w;
      }
      *reinterpret_cast<float4*>(&sv[ii][tid * 4]) = a;
    }
  } else {
#pragma unroll
    for (int ii = 0; ii < IG; ++ii) {
      const float* src = hidden + (size_t)(i0 + ii) * T_DIM * H_DIM +
                         (size_t)(T_DIM - 1) * H_DIM + tid * 4;
      *reinterpret_cast<float4*>(&sv[ii][tid * 4]) = *reinterpret_cast<const float4*>(src);
    }
  }
  __syncthreads();
  const int hl = tid >> 2;        // output row within block: 0..63
  const int kq = tid & 3;         // 4 lanes split K, contiguous 64B per group
  const float* wr = W + (size_t)(h0 + hl) * H_DIM + kq * 4;
  float acc[IG] = {};
#pragma unroll 8
  for (int j = 0; j < 64; ++j) {
    float4 w4 = *reinterpret_cast<const float4*>(wr + j * 16);
#pragma unroll
    for (int ii = 0; ii < IG; ++ii) {
      float4 s4 = *reinterpret_cast<const float4*>(&sv[ii][kq * 4 + j * 16]);
      acc[ii] += w4.x * s4.x + w4.y * s4.y + w4.z * s4.z + w4.w * s4.w;
    }
  }
#pragma unroll
  for (int ii = 0; ii < IG; ++ii) {
    acc[ii] += __shfl_xor(acc[ii], 1, 4);
    acc[ii] += __shfl_xor(acc[ii], 2, 4);
  }
  if (kq == 0) {
    float bb = bias[h0 + hl];
#pragma unroll
    for (int ii = 0; ii < IG; ++ii)
      dst[(size_t)(i0 + ii) * H_DIM + h0 + hl] = acc[ii] + bb;
  }
}

// ------- out[i,j,h] = tanh(rp[i,h] + xq[j,h])  [B,B,H] quirk. Grid-stride (G11). -------
__global__ void final_kernel(const float* __restrict__ rp, const float* __restrict__ xq,
                             float* __restrict__ out) {
  const int gt = blockIdx.x * 256 + threadIdx.x;
#pragma unroll
  for (int idx = gt; idx < 1048576; idx += STRIDE_NTHR) {  // 2 iters exact
    int e = idx * 4;
    int i = e >> 16;
    int j = (e >> 10) & 63;
    int h = e & 1023;
    float4 a = *reinterpret_cast<const float4*>(&rp[i * H_DIM + h]);
    float4 b = *reinterpret_cast<const float4*>(&xq[j * H_DIM + h]);
    float4 o;
    o.x = tanh_fast(a.x + b.x);
    o.y = tanh_fast(a.y + b.y);
    o.z = tanh_fast(a.z + b.z);
    o.w = tanh_fast(a.w + b.w);
    *reinterpret_cast<float4*>(&out[e]) = o;
  }
}

extern "C" void kernel_launch(void* const* d_in, const int* in_sizes, int n_in,
                              void* d_out, int out_size, void* d_ws, size_t ws_size,
                              hipStream_t stream) {
  const float* hidden = (const float*)d_in[0];
  // aspect (1), W_v (4), b_v (5), w_b (7) cancel under softmax -> unused
  const float* W_h = (const float*)d_in[2];
  const float* b_h = (const float*)d_in[3];
  const float* w_w = (const float*)d_in[6];  // use first H entries
  const float* W_p = (const float*)d_in[8];
  const float* b_p = (const float*)d_in[9];
  const float* W_x = (const float*)d_in[10];
  const float* b_x = (const float*)d_in[11];
  float* out = (float*)d_out;

  // Workspace liveness:
  //   hidBf  [0, 64M)            written prep, read gemm+wsum, DEAD after wsum
  //   whBf   [64M, 66M)          written prep, read gemm, DEAD after gemm
  //   r8     aliases whBf        written wsum, read rowvec2
  //   scoresP[66M, +512K)        written gemm8 (4 n-panel partials), read wsum
  //   rpB/xqB alias hidBf head   written rowvec2, read final
  char* ws = (char*)d_ws;
  __bf16* hidBf = (__bf16*)ws;                  // 64 MB  [0, 67108864)
  __bf16* whBf = (__bf16*)(ws + 67108864);      // 2 MB   [67108864, 69206016)
  float* r8 = (float*)(ws + 67108864);          // 2 MB, ALIASES whBf
  float* scoresP = (float*)(ws + 69206016);     // 512 KB [69206016, 69730304)
  float* rpB = (float*)ws;                      // 256 KB, ALIASES hidBf head
  float* xqB = (float*)(ws + 262144);           // 256 KB, ALIASES hidBf

  // 1) cvt hidden + cvt W_h (grid-stride, 2048 blocks)
  prep_kernel<<<2048, 256, 0, stream>>>(hidden, hidBf, W_h, whBf);

  // 2) 8-phase pipelined fused GEMM -> scoresP (512 blocks x 512 threads, 128 KiB LDS)
  gemm8_kernel<<<512, 512, 0, stream>>>(hidBf, whBf, b_h, w_w, scoresP);

  // 3) softmax (sums 4 partials) + weighted-sum partials (512 blocks)
  wsum_kernel<<<512, 256, 0, stream>>>(scoresP, hidBf, r8);

  // 4) rp and xq in one launch
  rowvec2_kernel<<<dim3(H_DIM / 64, B_DIM / IG, 2), 256, 0, stream>>>(
      r8, hidden, W_p, b_p, W_x, b_x, rpB, xqB);

  // 5) out[i,j,h] = tanh(rp[i,h] + xq[j,h]) (grid-stride, 2048 blocks)
  final_kernel<<<2048, 256, 0, stream>>>(rpB, xqB, out);
}

// Round 9
// 353.937 us; speedup vs baseline: 1.0152x; 1.0152x over previous
//
#include <hip/hip_runtime.h>
#include <hip/hip_bf16.h>
#include <stdint.h>

// Problem dims (fixed by reference): B=64, T=512, H=1024, A=300
#define B_DIM 64
#define T_DIM 512
#define H_DIM 1024
#define K_DIM 1024
#define M_DIM (B_DIM * T_DIM)  // 32768 rows of the big GEMM
#define IG 4

typedef __bf16 bf16x8 __attribute__((ext_vector_type(8)));
typedef float f32x4 __attribute__((ext_vector_type(4)));

__device__ __forceinline__ float tanh_fast(float x) {
  float e = __expf(2.0f * x);
  return 1.0f - 2.0f / (e + 1.0f);
}

__device__ __forceinline__ float bf2f(unsigned short u) {
  return __uint_as_float(((unsigned int)u) << 16);
}

// async global->LDS, 16B per lane. LDS dest must be wave-uniform base + lane*16.
__device__ __forceinline__ void async_cp16(const void* gp, void* lp) {
  __builtin_amdgcn_global_load_lds(
      reinterpret_cast<const __attribute__((address_space(1))) uint32_t*>(
          reinterpret_cast<uintptr_t>(gp)),
      reinterpret_cast<__attribute__((address_space(3))) uint32_t*>(
          reinterpret_cast<uintptr_t>(lp)),
      16, 0, 0);
}

__device__ __forceinline__ void cvt4(const float4& v, uint2* dst) {
  union { __bf16 b[4]; uint2 u; } o;
  o.b[0] = (__bf16)v.x; o.b[1] = (__bf16)v.y; o.b[2] = (__bf16)v.z; o.b[3] = (__bf16)v.w;
  *dst = o.u;
}

// ---- prep: cvt hidden + cvt W_h. Grid-stride, 2048 blocks (G11). ----
#define STRIDE_NTHR (2048 * 256)
__global__ void prep_kernel(const float* __restrict__ hidden, __bf16* __restrict__ hidBf,
                            const float* __restrict__ Wh, __bf16* __restrict__ whBf) {
  const int gt = blockIdx.x * 256 + threadIdx.x;  // 524288 threads
  const float4* hs = reinterpret_cast<const float4*>(hidden);
  uint2* hd = reinterpret_cast<uint2*>(hidBf);
#pragma unroll 4
  for (int i = gt; i < 8388608; i += STRIDE_NTHR) {  // 16 iters exact
    cvt4(hs[i], &hd[i]);
  }
  const float4* wsrc = reinterpret_cast<const float4*>(Wh);
  uint2* wd = reinterpret_cast<uint2*>(whBf);
  if (gt < 262144) cvt4(wsrc[gt], &wd[gt]);  // W_h: 262144 float4
}

// =============== gemm8: counted-vmcnt pipelined GEMM + tanh + dot -> scoresP ===============
// R7-verified version, byte-for-byte (85.3us, MfmaUtil 33.4, conflicts 0).
// 256x256 tile, 8 waves (2 wm x 4 wn, each 128x64), BK=32, 4 LDS buffers
// (128 KiB), prefetch distance 3, one barrier per K-tile with vmcnt(8) (never 0
// in the main loop; drain 8->4->0 in the epilogue tiles). R8's 6-barrier phase
// split REGRESSED (116us, MfmaUtil 24.5) -> reverted; gemm structure is frozen.
__global__ __launch_bounds__(512, 2) void gemm8_kernel(
    const __bf16* __restrict__ A, const __bf16* __restrict__ Bm,
    const float* __restrict__ bh, const float* __restrict__ ww,
    float* __restrict__ scoresP) {
  __shared__ __attribute__((aligned(16))) __bf16 lA[4 * 8192];  // 64 KB
  __shared__ __attribute__((aligned(16))) __bf16 lB[4 * 8192];  // 64 KB
  const int tid = threadIdx.x;
  const int bid = blockIdx.x;
  const int m0 = (bid & 127) * 256;   // consecutive bids share n-panel (A L2 reuse)
  const int nIdx = bid >> 7;          // 0..3
  const int n0 = nIdx * 256;
  const int wid = tid >> 6, lane = tid & 63;
  const int wm = wid >> 2, wn = wid & 3;
  const int r16 = lane & 15, quad = lane >> 4;
  const int sw2 = (r16 >> 1) & 3;

  // staging: thread covers chunks c = j*512+tid; row=c>>2, phys p=c&3,
  // logical kc = p ^ ((row>>1)&3). LDS dest = buf + c*16B (lane-contiguous).
  int srow[2], skc[2];
#pragma unroll
  for (int j = 0; j < 2; ++j) {
    int c = j * 512 + tid;
    srow[j] = c >> 2;
    skc[j] = (c & 3) ^ ((srow[j] >> 1) & 3);
  }
  // fragment read offsets (elems). row = base+r16 => (row>>1)&3 == sw2.
  int offA[8], offB[4];
#pragma unroll
  for (int mi = 0; mi < 8; ++mi)
    offA[mi] = (wm * 128 + mi * 16 + r16) * 32 + (quad ^ sw2) * 8;
#pragma unroll
  for (int ni = 0; ni < 4; ++ni)
    offB[ni] = (wn * 64 + ni * 16 + r16) * 32 + (quad ^ sw2) * 8;

  auto stageA = [&](int ts, int bs) {
#pragma unroll
    for (int j = 0; j < 2; ++j)
      async_cp16(A + (size_t)(m0 + srow[j]) * K_DIM + ts * 32 + skc[j] * 8,
                 lA + bs * 8192 + (j * 512 + tid) * 8);
  };
  auto stageB = [&](int ts, int bs) {
#pragma unroll
    for (int j = 0; j < 2; ++j)
      async_cp16(Bm + (size_t)(n0 + srow[j]) * K_DIM + ts * 32 + skc[j] * 8,
                 lB + bs * 8192 + (j * 512 + tid) * 8);
  };

  f32x4 acc[8][4] = {};

  auto tile = [&](int t, bool st) {
    const __bf16* lab = lA + (t & 3) * 8192;
    const __bf16* lbb = lB + (t & 3) * 8192;
    if (st) stageA(t + 3, (t + 3) & 3);
    bf16x8 bf[4];
#pragma unroll
    for (int ni = 0; ni < 4; ++ni)
      bf[ni] = *reinterpret_cast<const bf16x8*>(lbb + offB[ni]);
    bf16x8 af0[4];
#pragma unroll
    for (int mi = 0; mi < 4; ++mi)
      af0[mi] = *reinterpret_cast<const bf16x8*>(lab + offA[mi]);
    __builtin_amdgcn_s_setprio(1);
#pragma unroll
    for (int mi = 0; mi < 4; ++mi)
#pragma unroll
      for (int ni = 0; ni < 4; ++ni)
        acc[mi][ni] = __builtin_amdgcn_mfma_f32_16x16x32_bf16(af0[mi], bf[ni], acc[mi][ni], 0, 0, 0);
    __builtin_amdgcn_s_setprio(0);
    if (st) stageB(t + 3, (t + 3) & 3);
    bf16x8 af1[4];
#pragma unroll
    for (int mi = 0; mi < 4; ++mi)
      af1[mi] = *reinterpret_cast<const bf16x8*>(lab + offA[4 + mi]);
    __builtin_amdgcn_s_setprio(1);
#pragma unroll
    for (int mi = 0; mi < 4; ++mi)
#pragma unroll
      for (int ni = 0; ni < 4; ++ni)
        acc[4 + mi][ni] = __builtin_amdgcn_mfma_f32_16x16x32_bf16(af1[mi], bf[ni], acc[4 + mi][ni], 0, 0, 0);
    __builtin_amdgcn_s_setprio(0);
  };

  // prologue: stage tiles 0,1,2 in phase order (12 loads in flight)
  stageA(0, 0); stageB(0, 0);
  stageA(1, 1); stageB(1, 1);
  stageA(2, 2); stageB(2, 2);

#pragma unroll 1
  for (int t = 0; t < 29; ++t) {
    asm volatile("s_waitcnt vmcnt(8)" ::: "memory");
    __builtin_amdgcn_s_barrier();
    __builtin_amdgcn_sched_barrier(0);
    tile(t, true);
  }
  // epilogue tiles: no stages; drain 8 -> 4 -> 0
  asm volatile("s_waitcnt vmcnt(8)" ::: "memory");
  __builtin_amdgcn_s_barrier();
  __builtin_amdgcn_sched_barrier(0);
  tile(29, false);
  asm volatile("s_waitcnt vmcnt(4)" ::: "memory");
  __builtin_amdgcn_s_barrier();
  __builtin_amdgcn_sched_barrier(0);
  tile(30, false);
  asm volatile("s_waitcnt vmcnt(0)" ::: "memory");
  __builtin_amdgcn_s_barrier();
  __builtin_amdgcn_sched_barrier(0);
  tile(31, false);
  __syncthreads();

  // ---- fused epilogue: tanh + dot(ww) + 16-lane shfl + 4-way wn LDS reduction ----
  float* sBuf = reinterpret_cast<float*>(lA);  // 4 KB scratch, safe after syncthreads
  float bhv[4], wwv[4];
#pragma unroll
  for (int ni = 0; ni < 4; ++ni) {
    int n = n0 + wn * 64 + ni * 16 + r16;
    bhv[ni] = bh[n];
    wwv[ni] = ww[n];
  }
#pragma unroll
  for (int mi = 0; mi < 8; ++mi) {
#pragma unroll
    for (int rg = 0; rg < 4; ++rg) {
      float s = 0.f;
#pragma unroll
      for (int ni = 0; ni < 4; ++ni)
        s += tanh_fast(acc[mi][ni][rg] + bhv[ni]) * wwv[ni];
      s += __shfl_xor(s, 1, 16);
      s += __shfl_xor(s, 2, 16);
      s += __shfl_xor(s, 4, 16);
      s += __shfl_xor(s, 8, 16);
      if (r16 == 0) sBuf[wn * 256 + wm * 128 + mi * 16 + quad * 4 + rg] = s;
    }
  }
  __syncthreads();
  if (tid < 256) {
    scoresP[nIdx * M_DIM + m0 + tid] =
        sBuf[tid] + sBuf[256 + tid] + sBuf[512 + tid] + sBuf[768 + tid];
  }
}

// ------- wsum16: softmax + weighted-sum partials at 4 blocks/CU -------
// R3's mega run measured the 2-blocks/CU occupancy cliff for streaming loops;
// old wsum ran 512 blocks (2/CU). Now 1024 blocks (4/CU): block (b = bid>>4,
// tc = bid&15) covers 32 t-rows, writes a partial to r16[b][tc][H]. Partial
// traffic 4 MB (written once, read once by rowvec2 from L2/L3) — NOT the 4x
// traffic bundle that confounded R4's attempt. Softmax recomputed per block
// from the 4 n-panel scoresP partials (8 KB L2-resident reads).
__global__ void wsum_kernel(const float* __restrict__ scoresP,
                            const __bf16* __restrict__ hiddenBf,
                            float* __restrict__ r16) {
  __shared__ float sc[512];
  __shared__ float al[32];
  __shared__ float red[8];
  const int bid = blockIdx.x, tid = threadIdx.x;
  const int b = bid >> 4, tc = bid & 15;
  const int wv = tid >> 6, lane = tid & 63;
  float v0 = 0.f, v1 = 0.f;
#pragma unroll
  for (int p = 0; p < 4; ++p) {
    v0 += scoresP[p * M_DIM + b * T_DIM + tid];
    v1 += scoresP[p * M_DIM + b * T_DIM + 256 + tid];
  }
  sc[tid] = v0;
  sc[tid + 256] = v1;
  float mx = fmaxf(v0, v1);
#pragma unroll
  for (int off = 1; off < 64; off <<= 1) mx = fmaxf(mx, __shfl_xor(mx, off, 64));
  if (lane == 0) red[wv] = mx;
  __syncthreads();
  mx = fmaxf(fmaxf(red[0], red[1]), fmaxf(red[2], red[3]));
  float e0 = __expf(v0 - mx), e1 = __expf(v1 - mx);
  float s = e0 + e1;
#pragma unroll
  for (int off = 1; off < 64; off <<= 1) s += __shfl_xor(s, off, 64);
  if (lane == 0) red[4 + wv] = s;
  __syncthreads();
  float inv = 1.0f / (red[4] + red[5] + red[6] + red[7]);
  if (tid < 32) al[tid] = __expf(sc[tc * 32 + tid] - mx) * inv;
  __syncthreads();
  const __bf16* hp = hiddenBf + (size_t)b * T_DIM * H_DIM + (size_t)tc * 32 * H_DIM + tid * 4;
  float4 acc = make_float4(0.f, 0.f, 0.f, 0.f);
#pragma unroll 8
  for (int t = 0; t < 32; ++t) {
    float a = al[t];
    ushort4 u = *reinterpret_cast<const ushort4*>(hp + (size_t)t * H_DIM);
    acc.x += a * bf2f(u.x);
    acc.y += a * bf2f(u.y);
    acc.z += a * bf2f(u.z);
    acc.w += a * bf2f(u.w);
  }
  *reinterpret_cast<float4*>(r16 + (size_t)(b * 16 + tc) * H_DIM + tid * 4) = acc;
}

// ---- rp = (sum_tc parts) @ W_p^T + b_p ; xq = hidden[:,-1,:] @ W_x^T + b_x ----
// grid (H/64, B/IG, 2). NP=16 partials (compile-time, fully unrolled staging sum;
// 16x16KB L2/L3-resident reads per which==0 block).
template <int NP>
__global__ void rowvec2_kernel(const float* __restrict__ parts,
                               const float* __restrict__ hidden,
                               const float* __restrict__ W_p, const float* __restrict__ b_p,
                               const float* __restrict__ W_x, const float* __restrict__ b_x,
                               float* __restrict__ rp, float* __restrict__ xq) {
  __shared__ __attribute__((aligned(16))) float sv[IG][H_DIM];
  const int h0 = blockIdx.x * 64;
  const int i0 = blockIdx.y * IG;
  const int which = blockIdx.z;
  const int tid = threadIdx.x;
  const float* W = which ? W_x : W_p;
  const float* bias = which ? b_x : b_p;
  float* dst = which ? xq : rp;
  if (which == 0) {
#pragma unroll
    for (int ii = 0; ii < IG; ++ii) {
      const float* src = parts + (size_t)(i0 + ii) * NP * H_DIM + tid * 4;
      float4 a = *reinterpret_cast<const float4*>(src);
#pragma unroll
      for (int tc = 1; tc < NP; ++tc) {
        float4 v = *reinterpret_cast<const float4*>(src + (size_t)tc * H_DIM);
        a.x += v.x; a.y += v.y; a.z += v.z; a.w += v.w;
      }
      *reinterpret_cast<float4*>(&sv[ii][tid * 4]) = a;
    }
  } else {
#pragma unroll
    for (int ii = 0; ii < IG; ++ii) {
      const float* src = hidden + (size_t)(i0 + ii) * T_DIM * H_DIM +
                         (size_t)(T_DIM - 1) * H_DIM + tid * 4;
      *reinterpret_cast<float4*>(&sv[ii][tid * 4]) = *reinterpret_cast<const float4*>(src);
    }
  }
  __syncthreads();
  const int hl = tid >> 2;        // output row within block: 0..63
  const int kq = tid & 3;         // 4 lanes split K, contiguous 64B per group
  const float* wr = W + (size_t)(h0 + hl) * H_DIM + kq * 4;
  float acc[IG] = {};
#pragma unroll 8
  for (int j = 0; j < 64; ++j) {
    float4 w4 = *reinterpret_cast<const float4*>(wr + j * 16);
#pragma unroll
    for (int ii = 0; ii < IG; ++ii) {
      float4 s4 = *reinterpret_cast<const float4*>(&sv[ii][kq * 4 + j * 16]);
      acc[ii] += w4.x * s4.x + w4.y * s4.y + w4.z * s4.z + w4.w * s4.w;
    }
  }
#pragma unroll
  for (int ii = 0; ii < IG; ++ii) {
    acc[ii] += __shfl_xor(acc[ii], 1, 4);
    acc[ii] += __shfl_xor(acc[ii], 2, 4);
  }
  if (kq == 0) {
    float bb = bias[h0 + hl];
#pragma unroll
    for (int ii = 0; ii < IG; ++ii)
      dst[(size_t)(i0 + ii) * H_DIM + h0 + hl] = acc[ii] + bb;
  }
}

// ------- out[i,j,h] = tanh(rp[i,h] + xq[j,h])  [B,B,H] quirk. Grid-stride (G11). -------
__global__ void final_kernel(const float* __restrict__ rp, const float* __restrict__ xq,
                             float* __restrict__ out) {
  const int gt = blockIdx.x * 256 + threadIdx.x;
#pragma unroll
  for (int idx = gt; idx < 1048576; idx += STRIDE_NTHR) {  // 2 iters exact
    int e = idx * 4;
    int i = e >> 16;
    int j = (e >> 10) & 63;
    int h = e & 1023;
    float4 a = *reinterpret_cast<const float4*>(&rp[i * H_DIM + h]);
    float4 b = *reinterpret_cast<const float4*>(&xq[j * H_DIM + h]);
    float4 o;
    o.x = tanh_fast(a.x + b.x);
    o.y = tanh_fast(a.y + b.y);
    o.z = tanh_fast(a.z + b.z);
    o.w = tanh_fast(a.w + b.w);
    *reinterpret_cast<float4*>(&out[e]) = o;
  }
}

extern "C" void kernel_launch(void* const* d_in, const int* in_sizes, int n_in,
                              void* d_out, int out_size, void* d_ws, size_t ws_size,
                              hipStream_t stream) {
  const float* hidden = (const float*)d_in[0];
  // aspect (1), W_v (4), b_v (5), w_b (7) cancel under softmax -> unused
  const float* W_h = (const float*)d_in[2];
  const float* b_h = (const float*)d_in[3];
  const float* w_w = (const float*)d_in[6];  // use first H entries
  const float* W_p = (const float*)d_in[8];
  const float* b_p = (const float*)d_in[9];
  const float* W_x = (const float*)d_in[10];
  const float* b_x = (const float*)d_in[11];
  float* out = (float*)d_out;

  // Workspace liveness:
  //   hidBf  [0, 64M)            written prep, read gemm+wsum, DEAD after wsum
  //   whBf   [64M, 66M)          written prep, read gemm, DEAD after gemm
  //   scoresP[66M, +512K)        written gemm8 (4 n-panel partials), read wsum
  //   r16    [+512K, +4M)        written wsum (16 partials/batch), read rowvec2
  //   rpB/xqB alias hidBf head   written rowvec2, read final (hidBf dead)
  char* ws = (char*)d_ws;
  __bf16* hidBf = (__bf16*)ws;                  // 64 MB  [0, 67108864)
  __bf16* whBf = (__bf16*)(ws + 67108864);      // 2 MB   [67108864, 69206016)
  float* scoresP = (float*)(ws + 69206016);     // 512 KB [69206016, 69730304)
  float* r16 = (float*)(ws + 69730304);         // 4 MB   [69730304, 73924608)
  float* rpB = (float*)ws;                      // 256 KB, ALIASES hidBf head
  float* xqB = (float*)(ws + 262144);           // 256 KB, ALIASES hidBf

  // 1) cvt hidden + cvt W_h (grid-stride, 2048 blocks)
  prep_kernel<<<2048, 256, 0, stream>>>(hidden, hidBf, W_h, whBf);

  // 2) pipelined fused GEMM -> scoresP (R7-verified, 512 blocks x 512 threads)
  gemm8_kernel<<<512, 512, 0, stream>>>(hidBf, whBf, b_h, w_w, scoresP);

  // 3) softmax + weighted-sum partials (1024 blocks = 4 blocks/CU)
  wsum_kernel<<<1024, 256, 0, stream>>>(scoresP, hidBf, r16);

  // 4) rp and xq in one launch (sums 16 partials)
  rowvec2_kernel<16><<<dim3(H_DIM / 64, B_DIM / IG, 2), 256, 0, stream>>>(
      r16, hidden, W_p, b_p, W_x, b_x, rpB, xqB);

  // 5) out[i,j,h] = tanh(rp[i,h] + xq[j,h]) (grid-stride, 2048 blocks)
  final_kernel<<<2048, 256, 0, stream>>>(rpB, xqB, out);
}

// Round 10
// 352.196 us; speedup vs baseline: 1.0202x; 1.0049x over previous
//
#include <hip/hip_runtime.h>
#include <hip/hip_bf16.h>
#include <stdint.h>

// Problem dims (fixed by reference): B=64, T=512, H=1024, A=300
#define B_DIM 64
#define T_DIM 512
#define H_DIM 1024
#define K_DIM 1024
#define M_DIM (B_DIM * T_DIM)  // 32768 rows of the big GEMM
#define IG 4

typedef __bf16 bf16x8 __attribute__((ext_vector_type(8)));
typedef float f32x4 __attribute__((ext_vector_type(4)));

__device__ __forceinline__ float tanh_fast(float x) {
  float e = __expf(2.0f * x);
  return 1.0f - 2.0f / (e + 1.0f);
}

__device__ __forceinline__ float bf2f(unsigned short u) {
  return __uint_as_float(((unsigned int)u) << 16);
}

// async global->LDS, 16B per lane. LDS dest must be wave-uniform base + lane*16.
__device__ __forceinline__ void async_cp16(const void* gp, void* lp) {
  __builtin_amdgcn_global_load_lds(
      reinterpret_cast<const __attribute__((address_space(1))) uint32_t*>(
          reinterpret_cast<uintptr_t>(gp)),
      reinterpret_cast<__attribute__((address_space(3))) uint32_t*>(
          reinterpret_cast<uintptr_t>(lp)),
      16, 0, 0);
}

__device__ __forceinline__ void cvt4(const float4& v, uint2* dst) {
  union { __bf16 b[4]; uint2 u; } o;
  o.b[0] = (__bf16)v.x; o.b[1] = (__bf16)v.y; o.b[2] = (__bf16)v.z; o.b[3] = (__bf16)v.w;
  *dst = o.u;
}

// ---- prep: cvt hidden (32768 blk) + cvt W_h (1024 blk). DENSE blocks (R1's
// 344us config; the grid-stride variant's 2MB-strided per-thread pattern
// regressed ~5-10us in clean runs R6-R9). No zero-scores: gemm8 writes
// scoresP non-atomically. ----
__global__ void prep_kernel(const float* __restrict__ hidden, __bf16* __restrict__ hidBf,
                            const float* __restrict__ Wh, __bf16* __restrict__ whBf) {
  const int bid = blockIdx.x, tid = threadIdx.x;
  if (bid < 32768) {
    int i = bid * 256 + tid;
    float4 v = reinterpret_cast<const float4*>(hidden)[i];
    cvt4(v, &reinterpret_cast<uint2*>(hidBf)[i]);
  } else {
    int i = (bid - 32768) * 256 + tid;
    float4 v = reinterpret_cast<const float4*>(Wh)[i];
    cvt4(v, &reinterpret_cast<uint2*>(whBf)[i]);
  }
}

// =============== gemm8: counted-vmcnt pipelined GEMM + tanh + dot -> scoresP ===============
// FROZEN (R7/R9-verified, 85-86us, MfmaUtil ~34, conflicts 0). 256x256 tile,
// 8 waves (2wm x 4wn, each 128x64), BK=32, 4 LDS buffers (128 KiB), prefetch
// depth 3, vmcnt(8) in main loop (never 0), drain 8->4->0. Non-atomic partial
// stores (4-way wn LDS reduction; unique (nIdx,m) writer). Structure attempts
// R8 (6-barrier phase split, m141-style sched_barrier pinning) REGRESSED.
__global__ __launch_bounds__(512, 2) void gemm8_kernel(
    const __bf16* __restrict__ A, const __bf16* __restrict__ Bm,
    const float* __restrict__ bh, const float* __restrict__ ww,
    float* __restrict__ scoresP) {
  __shared__ __attribute__((aligned(16))) __bf16 lA[4 * 8192];  // 64 KB
  __shared__ __attribute__((aligned(16))) __bf16 lB[4 * 8192];  // 64 KB
  const int tid = threadIdx.x;
  const int bid = blockIdx.x;
  const int m0 = (bid & 127) * 256;   // consecutive bids share n-panel (A L2 reuse)
  const int nIdx = bid >> 7;          // 0..3
  const int n0 = nIdx * 256;
  const int wid = tid >> 6, lane = tid & 63;
  const int wm = wid >> 2, wn = wid & 3;
  const int r16 = lane & 15, quad = lane >> 4;
  const int sw2 = (r16 >> 1) & 3;

  int srow[2], skc[2];
#pragma unroll
  for (int j = 0; j < 2; ++j) {
    int c = j * 512 + tid;
    srow[j] = c >> 2;
    skc[j] = (c & 3) ^ ((srow[j] >> 1) & 3);
  }
  int offA[8], offB[4];
#pragma unroll
  for (int mi = 0; mi < 8; ++mi)
    offA[mi] = (wm * 128 + mi * 16 + r16) * 32 + (quad ^ sw2) * 8;
#pragma unroll
  for (int ni = 0; ni < 4; ++ni)
    offB[ni] = (wn * 64 + ni * 16 + r16) * 32 + (quad ^ sw2) * 8;

  auto stageA = [&](int ts, int bs) {
#pragma unroll
    for (int j = 0; j < 2; ++j)
      async_cp16(A + (size_t)(m0 + srow[j]) * K_DIM + ts * 32 + skc[j] * 8,
                 lA + bs * 8192 + (j * 512 + tid) * 8);
  };
  auto stageB = [&](int ts, int bs) {
#pragma unroll
    for (int j = 0; j < 2; ++j)
      async_cp16(Bm + (size_t)(n0 + srow[j]) * K_DIM + ts * 32 + skc[j] * 8,
                 lB + bs * 8192 + (j * 512 + tid) * 8);
  };

  f32x4 acc[8][4] = {};

  auto tile = [&](int t, bool st) {
    const __bf16* lab = lA + (t & 3) * 8192;
    const __bf16* lbb = lB + (t & 3) * 8192;
    if (st) stageA(t + 3, (t + 3) & 3);
    bf16x8 bf[4];
#pragma unroll
    for (int ni = 0; ni < 4; ++ni)
      bf[ni] = *reinterpret_cast<const bf16x8*>(lbb + offB[ni]);
    bf16x8 af0[4];
#pragma unroll
    for (int mi = 0; mi < 4; ++mi)
      af0[mi] = *reinterpret_cast<const bf16x8*>(lab + offA[mi]);
    __builtin_amdgcn_s_setprio(1);
#pragma unroll
    for (int mi = 0; mi < 4; ++mi)
#pragma unroll
      for (int ni = 0; ni < 4; ++ni)
        acc[mi][ni] = __builtin_amdgcn_mfma_f32_16x16x32_bf16(af0[mi], bf[ni], acc[mi][ni], 0, 0, 0);
    __builtin_amdgcn_s_setprio(0);
    if (st) stageB(t + 3, (t + 3) & 3);
    bf16x8 af1[4];
#pragma unroll
    for (int mi = 0; mi < 4; ++mi)
      af1[mi] = *reinterpret_cast<const bf16x8*>(lab + offA[4 + mi]);
    __builtin_amdgcn_s_setprio(1);
#pragma unroll
    for (int mi = 0; mi < 4; ++mi)
#pragma unroll
      for (int ni = 0; ni < 4; ++ni)
        acc[4 + mi][ni] = __builtin_amdgcn_mfma_f32_16x16x32_bf16(af1[mi], bf[ni], acc[4 + mi][ni], 0, 0, 0);
    __builtin_amdgcn_s_setprio(0);
  };

  // prologue: stage tiles 0,1,2 (12 loads/wave in flight)
  stageA(0, 0); stageB(0, 0);
  stageA(1, 1); stageB(1, 1);
  stageA(2, 2); stageB(2, 2);

#pragma unroll 1
  for (int t = 0; t < 29; ++t) {
    asm volatile("s_waitcnt vmcnt(8)" ::: "memory");
    __builtin_amdgcn_s_barrier();
    __builtin_amdgcn_sched_barrier(0);
    tile(t, true);
  }
  asm volatile("s_waitcnt vmcnt(8)" ::: "memory");
  __builtin_amdgcn_s_barrier();
  __builtin_amdgcn_sched_barrier(0);
  tile(29, false);
  asm volatile("s_waitcnt vmcnt(4)" ::: "memory");
  __builtin_amdgcn_s_barrier();
  __builtin_amdgcn_sched_barrier(0);
  tile(30, false);
  asm volatile("s_waitcnt vmcnt(0)" ::: "memory");
  __builtin_amdgcn_s_barrier();
  __builtin_amdgcn_sched_barrier(0);
  tile(31, false);
  __syncthreads();

  // ---- fused epilogue: tanh + dot(ww) + 16-lane shfl + 4-way wn LDS reduction ----
  float* sBuf = reinterpret_cast<float*>(lA);  // 4 KB scratch, safe after syncthreads
  float bhv[4], wwv[4];
#pragma unroll
  for (int ni = 0; ni < 4; ++ni) {
    int n = n0 + wn * 64 + ni * 16 + r16;
    bhv[ni] = bh[n];
    wwv[ni] = ww[n];
  }
#pragma unroll
  for (int mi = 0; mi < 8; ++mi) {
#pragma unroll
    for (int rg = 0; rg < 4; ++rg) {
      float s = 0.f;
#pragma unroll
      for (int ni = 0; ni < 4; ++ni)
        s += tanh_fast(acc[mi][ni][rg] + bhv[ni]) * wwv[ni];
      s += __shfl_xor(s, 1, 16);
      s += __shfl_xor(s, 2, 16);
      s += __shfl_xor(s, 4, 16);
      s += __shfl_xor(s, 8, 16);
      if (r16 == 0) sBuf[wn * 256 + wm * 128 + mi * 16 + quad * 4 + rg] = s;
    }
  }
  __syncthreads();
  if (tid < 256) {
    scoresP[nIdx * M_DIM + m0 + tid] =
        sBuf[tid] + sBuf[256 + tid] + sBuf[512 + tid] + sBuf[768 + tid];
  }
}

// ------- wsum (R1's 344us body verbatim, 512 blocks, al[64]/8-tc): softmax +
// weighted-sum partials. Only change vs R1: scores row = sum of the 4 n-panel
// scoresP partials (L2-resident) instead of one atomic-built array. -------
__global__ void wsum_kernel(const float* __restrict__ scoresP,
                            const __bf16* __restrict__ hiddenBf,
                            float* __restrict__ r8) {
  __shared__ float sc[512];
  __shared__ float al[64];
  __shared__ float red[8];
  const int bid = blockIdx.x, tid = threadIdx.x;
  const int b = bid >> 3, tc = bid & 7;
  const int wv = tid >> 6, lane = tid & 63;
  float v0 = 0.f, v1 = 0.f;
#pragma unroll
  for (int p = 0; p < 4; ++p) {
    v0 += scoresP[p * M_DIM + b * T_DIM + tid];
    v1 += scoresP[p * M_DIM + b * T_DIM + 256 + tid];
  }
  sc[tid] = v0;
  sc[tid + 256] = v1;
  float mx = fmaxf(v0, v1);
#pragma unroll
  for (int off = 1; off < 64; off <<= 1) mx = fmaxf(mx, __shfl_xor(mx, off, 64));
  if (lane == 0) red[wv] = mx;
  __syncthreads();
  mx = fmaxf(fmaxf(red[0], red[1]), fmaxf(red[2], red[3]));
  float e0 = __expf(v0 - mx), e1 = __expf(v1 - mx);
  float s = e0 + e1;
#pragma unroll
  for (int off = 1; off < 64; off <<= 1) s += __shfl_xor(s, off, 64);
  if (lane == 0) red[4 + wv] = s;
  __syncthreads();
  float inv = 1.0f / (red[4] + red[5] + red[6] + red[7]);
  if (tid < 64) al[tid] = __expf(sc[tc * 64 + tid] - mx) * inv;
  __syncthreads();
  const __bf16* hp = hiddenBf + (size_t)b * T_DIM * H_DIM + (size_t)tc * 64 * H_DIM + tid * 4;
  float4 acc = make_float4(0.f, 0.f, 0.f, 0.f);
#pragma unroll 8
  for (int t = 0; t < 64; ++t) {
    float a = al[t];
    ushort4 u = *reinterpret_cast<const ushort4*>(hp + (size_t)t * H_DIM);
    acc.x += a * bf2f(u.x);
    acc.y += a * bf2f(u.y);
    acc.z += a * bf2f(u.z);
    acc.w += a * bf2f(u.w);
  }
  *reinterpret_cast<float4*>(r8 + (size_t)(b * 8 + tc) * H_DIM + tid * 4) = acc;
}

// ---- rp = (sum_tc r8) @ W_p^T + b_p ; xq = hidden[:,-1,:] @ W_x^T + b_x ----
// R1's 344us body verbatim (NP=8). grid (H/64, B/IG, 2).
__global__ void rowvec2_kernel(const float* __restrict__ r8,
                               const float* __restrict__ hidden,
                               const float* __restrict__ W_p, const float* __restrict__ b_p,
                               const float* __restrict__ W_x, const float* __restrict__ b_x,
                               float* __restrict__ rp, float* __restrict__ xq) {
  __shared__ __attribute__((aligned(16))) float sv[IG][H_DIM];
  const int h0 = blockIdx.x * 64;
  const int i0 = blockIdx.y * IG;
  const int which = blockIdx.z;
  const int tid = threadIdx.x;
  const float* W = which ? W_x : W_p;
  const float* bias = which ? b_x : b_p;
  float* dst = which ? xq : rp;
  if (which == 0) {
#pragma unroll
    for (int ii = 0; ii < IG; ++ii) {
      const float* src = r8 + (size_t)(i0 + ii) * 8 * H_DIM + tid * 4;
      float4 a = *reinterpret_cast<const float4*>(src);
#pragma unroll
      for (int tc = 1; tc < 8; ++tc) {
        float4 v = *reinterpret_cast<const float4*>(src + (size_t)tc * H_DIM);
        a.x += v.x; a.y += v.y; a.z += v.z; a.w += v.w;
      }
      *reinterpret_cast<float4*>(&sv[ii][tid * 4]) = a;
    }
  } else {
#pragma unroll
    for (int ii = 0; ii < IG; ++ii) {
      const float* src = hidden + (size_t)(i0 + ii) * T_DIM * H_DIM +
                         (size_t)(T_DIM - 1) * H_DIM + tid * 4;
      *reinterpret_cast<float4*>(&sv[ii][tid * 4]) = *reinterpret_cast<const float4*>(src);
    }
  }
  __syncthreads();
  const int hl = tid >> 2;        // output row within block: 0..63
  const int kq = tid & 3;         // 4 lanes split K, contiguous 64B per group
  const float* wr = W + (size_t)(h0 + hl) * H_DIM + kq * 4;
  float acc[IG] = {};
#pragma unroll 8
  for (int j = 0; j < 64; ++j) {
    float4 w4 = *reinterpret_cast<const float4*>(wr + j * 16);
#pragma unroll
    for (int ii = 0; ii < IG; ++ii) {
      float4 s4 = *reinterpret_cast<const float4*>(&sv[ii][kq * 4 + j * 16]);
      acc[ii] += w4.x * s4.x + w4.y * s4.y + w4.z * s4.z + w4.w * s4.w;
    }
  }
#pragma unroll
  for (int ii = 0; ii < IG; ++ii) {
    acc[ii] += __shfl_xor(acc[ii], 1, 4);
    acc[ii] += __shfl_xor(acc[ii], 2, 4);
  }
  if (kq == 0) {
    float bb = bias[h0 + hl];
#pragma unroll
    for (int ii = 0; ii < IG; ++ii)
      dst[(size_t)(i0 + ii) * H_DIM + h0 + hl] = acc[ii] + bb;
  }
}

// ------- out[i,j,h] = tanh(rp[i,h] + xq[j,h])  [B,B,H] quirk. DENSE 4096 blocks
// (R1's 344us config; grid-stride variant regressed). -------
__global__ void final_kernel(const float* __restrict__ rp, const float* __restrict__ xq,
                             float* __restrict__ out) {
  int idx = blockIdx.x * 256 + threadIdx.x;  // one float4 each
  int e = idx * 4;
  int i = e >> 16;
  int j = (e >> 10) & 63;
  int h = e & 1023;
  float4 a = *reinterpret_cast<const float4*>(&rp[i * H_DIM + h]);
  float4 b = *reinterpret_cast<const float4*>(&xq[j * H_DIM + h]);
  float4 o;
  o.x = tanh_fast(a.x + b.x);
  o.y = tanh_fast(a.y + b.y);
  o.z = tanh_fast(a.z + b.z);
  o.w = tanh_fast(a.w + b.w);
  *reinterpret_cast<float4*>(&out[e]) = o;
}

extern "C" void kernel_launch(void* const* d_in, const int* in_sizes, int n_in,
                              void* d_out, int out_size, void* d_ws, size_t ws_size,
                              hipStream_t stream) {
  const float* hidden = (const float*)d_in[0];
  // aspect (1), W_v (4), b_v (5), w_b (7) cancel under softmax -> unused
  const float* W_h = (const float*)d_in[2];
  const float* b_h = (const float*)d_in[3];
  const float* w_w = (const float*)d_in[6];  // use first H entries
  const float* W_p = (const float*)d_in[8];
  const float* b_p = (const float*)d_in[9];
  const float* W_x = (const float*)d_in[10];
  const float* b_x = (const float*)d_in[11];
  float* out = (float*)d_out;

  // Workspace liveness:
  //   hidBf  [0, 64M)            written prep, read gemm+wsum, DEAD after wsum
  //   whBf   [64M, 66M)          written prep, read gemm, DEAD after gemm
  //   scoresP[66M, +512K)        written gemm8 (4 n-panel partials), read wsum
  //   r8     [+512K, +2M)        written wsum (8 partials/batch), read rowvec2
  //   rpB/xqB alias hidBf head   written rowvec2, read final (hidBf dead)
  char* ws = (char*)d_ws;
  __bf16* hidBf = (__bf16*)ws;                  // 64 MB  [0, 67108864)
  __bf16* whBf = (__bf16*)(ws + 67108864);      // 2 MB   [67108864, 69206016)
  float* scoresP = (float*)(ws + 69206016);     // 512 KB [69206016, 69730304)
  float* r8 = (float*)(ws + 69730304);          // 2 MB   [69730304, 71827456)
  float* rpB = (float*)ws;                      // 256 KB, ALIASES hidBf head
  float* xqB = (float*)(ws + 262144);           // 256 KB, ALIASES hidBf

  // 1) cvt hidden + cvt W_h (dense, 33792 blocks — R1 config)
  prep_kernel<<<33792, 256, 0, stream>>>(hidden, hidBf, W_h, whBf);

  // 2) pipelined fused GEMM -> scoresP (frozen, 512 blocks x 512 threads)
  gemm8_kernel<<<512, 512, 0, stream>>>(hidBf, whBf, b_h, w_w, scoresP);

  // 3) softmax (sums 4 partials) + weighted-sum partials (512 blocks — R1 config)
  wsum_kernel<<<512, 256, 0, stream>>>(scoresP, hidBf, r8);

  // 4) rp and xq in one launch (NP=8 — R1 config)
  rowvec2_kernel<<<dim3(H_DIM / 64, B_DIM / IG, 2), 256, 0, stream>>>(
      r8, hidden, W_p, b_p, W_x, b_x, rpB, xqB);

  // 5) out[i,j,h] = tanh(rp[i,h] + xq[j,h]) (dense, 4096 blocks — R1 config)
  final_kernel<<<4096, 256, 0, stream>>>(rpB, xqB, out);
}